// Round 6
// baseline (510.451 us; speedup 1.0000x reference)
//
#include <hip/hip_runtime.h>
#include <hip/hip_fp16.h>
#include <cstdint>

typedef _Float16 f16x8 __attribute__((ext_vector_type(8)));
typedef _Float16 f16x4 __attribute__((ext_vector_type(4)));
typedef float    f32x4 __attribute__((ext_vector_type(4)));

#define MFMA16(a, b, c) __builtin_amdgcn_mfma_f32_16x16x32_f16((a), (b), (c), 0, 0, 0)

// ---------------------------------------------------------------------------
// GEMM: C[m][n] = sum_k A[m][k] * B[n][k] + bias[n]
// A fp32 [M][K], B fp32 [N][K] (B^T-layout, K contiguous), C fp16 [M][N]
// Tile 64x64, BK=64, 256 threads (4 waves, each 32x32 = 2x2 MFMA tiles).
// LDS XOR-swizzle byte ^= (row&7)<<4 (G4: kills 16-way conflict on b128 reads)
// ---------------------------------------------------------------------------
__global__ __launch_bounds__(256) void k_qkv_gemm(
    const float* __restrict__ A, const float* __restrict__ B,
    const float* __restrict__ bias, _Float16* __restrict__ C,
    int M, int N, int K)
{
    __shared__ _Float16 lA[64 * 64];
    __shared__ _Float16 lB[64 * 64];
    const int t    = threadIdx.x;
    const int lane = t & 63, wv = t >> 6;
    const int wr = (wv >> 1) * 32, wc = (wv & 1) * 32;
    const int fr = lane & 15, fg = lane >> 4;
    const int srow = t >> 2;          // staging row 0..63
    const int scol = (t & 3) * 16;    // staging col base (elements)

    const float* Ag = A + (size_t)(blockIdx.x * 64 + srow) * K + scol;
    const float* Bg = B + (size_t)(blockIdx.y * 64 + srow) * K + scol;

    f32x4 acc[2][2] = {};

    for (int k0 = 0; k0 < K; k0 += 64) {
#pragma unroll
        for (int q = 0; q < 4; ++q) {
            float4 av = *(const float4*)(Ag + k0 + q * 4);
            float4 bv = *(const float4*)(Bg + k0 + q * 4);
            int bo = ((scol + q * 4) * 2) ^ ((srow & 7) << 4);
            f16x4 ah = { (_Float16)av.x, (_Float16)av.y, (_Float16)av.z, (_Float16)av.w };
            f16x4 bh = { (_Float16)bv.x, (_Float16)bv.y, (_Float16)bv.z, (_Float16)bv.w };
            *(f16x4*)((char*)lA + srow * 128 + bo) = ah;
            *(f16x4*)((char*)lB + srow * 128 + bo) = bh;
        }
        __syncthreads();
#pragma unroll
        for (int kc = 0; kc < 2; ++kc) {
            const int kb = kc * 64 + fg * 16;   // byte offset of k-chunk in row
            f16x8 a0, a1, b0, b1;
            { int r = wr + fr;      a0 = *(const f16x8*)((char*)lA + r * 128 + (kb ^ ((r & 7) << 4))); }
            { int r = wr + 16 + fr; a1 = *(const f16x8*)((char*)lA + r * 128 + (kb ^ ((r & 7) << 4))); }
            { int r = wc + fr;      b0 = *(const f16x8*)((char*)lB + r * 128 + (kb ^ ((r & 7) << 4))); }
            { int r = wc + 16 + fr; b1 = *(const f16x8*)((char*)lB + r * 128 + (kb ^ ((r & 7) << 4))); }
            acc[0][0] = MFMA16(a0, b0, acc[0][0]);
            acc[0][1] = MFMA16(a0, b1, acc[0][1]);
            acc[1][0] = MFMA16(a1, b0, acc[1][0]);
            acc[1][1] = MFMA16(a1, b1, acc[1][1]);
        }
        __syncthreads();
    }
    // epilogue: D layout col=lane&15 (n), row=(lane>>4)*4+r (m)  [verified m89]
#pragma unroll
    for (int mi = 0; mi < 2; ++mi)
#pragma unroll
        for (int ni = 0; ni < 2; ++ni) {
            const int col = blockIdx.y * 64 + wc + ni * 16 + fr;
            const float bb = bias[col];
#pragma unroll
            for (int r = 0; r < 4; ++r) {
                const int row = blockIdx.x * 64 + wr + mi * 16 + fg * 4 + r;
                C[(size_t)row * N + col] = (_Float16)(acc[mi][ni][r] + bb);
            }
        }
}

// ---------------------------------------------------------------------------
// Proj GEMM: A fp16 [M][512] with row stride lda (reads attn-out in the
// q-slice of the qkv buffer), B fp32 [N][K], C fp32 [M][N] (+bias)
// ---------------------------------------------------------------------------
__global__ __launch_bounds__(256) void k_proj_gemm(
    const _Float16* __restrict__ A, int lda, const float* __restrict__ B,
    const float* __restrict__ bias, float* __restrict__ C,
    int M, int N, int K)
{
    __shared__ _Float16 lA[64 * 64];
    __shared__ _Float16 lB[64 * 64];
    const int t    = threadIdx.x;
    const int lane = t & 63, wv = t >> 6;
    const int wr = (wv >> 1) * 32, wc = (wv & 1) * 32;
    const int fr = lane & 15, fg = lane >> 4;
    const int srow = t >> 2;
    const int scol = (t & 3) * 16;

    const _Float16* Ag = A + (size_t)(blockIdx.x * 64 + srow) * lda + scol;
    const float*    Bg = B + (size_t)(blockIdx.y * 64 + srow) * K + scol;

    f32x4 acc[2][2] = {};

    for (int k0 = 0; k0 < K; k0 += 64) {
#pragma unroll
        for (int q = 0; q < 2; ++q) {   // A already fp16: 2 x 16B per thread
            f16x8 av = *(const f16x8*)(Ag + k0 + q * 8);
            int bo = ((scol + q * 8) * 2) ^ ((srow & 7) << 4);
            *(f16x8*)((char*)lA + srow * 128 + bo) = av;
        }
#pragma unroll
        for (int q = 0; q < 4; ++q) {
            float4 bv = *(const float4*)(Bg + k0 + q * 4);
            int bo = ((scol + q * 4) * 2) ^ ((srow & 7) << 4);
            f16x4 bh = { (_Float16)bv.x, (_Float16)bv.y, (_Float16)bv.z, (_Float16)bv.w };
            *(f16x4*)((char*)lB + srow * 128 + bo) = bh;
        }
        __syncthreads();
#pragma unroll
        for (int kc = 0; kc < 2; ++kc) {
            const int kb = kc * 64 + fg * 16;
            f16x8 a0, a1, b0, b1;
            { int r = wr + fr;      a0 = *(const f16x8*)((char*)lA + r * 128 + (kb ^ ((r & 7) << 4))); }
            { int r = wr + 16 + fr; a1 = *(const f16x8*)((char*)lA + r * 128 + (kb ^ ((r & 7) << 4))); }
            { int r = wc + fr;      b0 = *(const f16x8*)((char*)lB + r * 128 + (kb ^ ((r & 7) << 4))); }
            { int r = wc + 16 + fr; b1 = *(const f16x8*)((char*)lB + r * 128 + (kb ^ ((r & 7) << 4))); }
            acc[0][0] = MFMA16(a0, b0, acc[0][0]);
            acc[0][1] = MFMA16(a0, b1, acc[0][1]);
            acc[1][0] = MFMA16(a1, b0, acc[1][0]);
            acc[1][1] = MFMA16(a1, b1, acc[1][1]);
        }
        __syncthreads();
    }
#pragma unroll
    for (int mi = 0; mi < 2; ++mi)
#pragma unroll
        for (int ni = 0; ni < 2; ++ni) {
            const int col = blockIdx.y * 64 + wc + ni * 16 + fr;
            const float bb = bias[col];
#pragma unroll
            for (int r = 0; r < 4; ++r) {
                const int row = blockIdx.x * 64 + wr + mi * 16 + fg * 4 + r;
                C[(size_t)row * N + col] = acc[mi][ni][r] + bb;
            }
        }
}

// ---------------------------------------------------------------------------
// Attention: one block (256 thr, 4 waves) per (b,h).  N=256 tokens, hd=32.
// qkv fp16 [32768][1536]: q at col h*32, k at 512+h*32, v at 1024+h*32.
// Output written IN PLACE over the q-slice (block (b,h) reads q cols
// [h*32,h*32+32) only before writing them; k/v cols never written -> safe).
// ---------------------------------------------------------------------------
#define ATT_SCALE 0.17677669529663687f  // 1/sqrt(32)

__global__ __launch_bounds__(256) void k_attn(
    _Float16* __restrict__ qkv, const float* __restrict__ rpb)
{
    __shared__ _Float16 lS[4][16 * 264];
    __shared__ _Float16 lVt[32 * 264];
    __shared__ float    lbias[945];

    const int bh = blockIdx.x;
    const int b = bh >> 4, h = bh & 15;
    const int t = threadIdx.x, wv = t >> 6, lane = t & 63;
    const int fr = lane & 15, fg = lane >> 4;

    _Float16* qkv_b0 = qkv + (size_t)b * 256 * 1536;

    // head's bias table slice -> LDS (945 floats)
    for (int p = t; p < 945; p += 256) lbias[p] = rpb[p * 16 + h];

    // V transposed into LDS: thread t owns V row t (32 halves)
    {
        const _Float16* vrow = qkv_b0 + (size_t)t * 1536 + 1024 + h * 32;
        f16x8 v0 = *(const f16x8*)(vrow);
        f16x8 v1 = *(const f16x8*)(vrow + 8);
        f16x8 v2 = *(const f16x8*)(vrow + 16);
        f16x8 v3 = *(const f16x8*)(vrow + 24);
#pragma unroll
        for (int d = 0; d < 8; ++d) {
            lVt[(d     ) * 264 + t] = v0[d];
            lVt[(d +  8) * 264 + t] = v1[d];
            lVt[(d + 16) * 264 + t] = v2[d];
            lVt[(d + 24) * 264 + t] = v3[d];
        }
    }
    __syncthreads();

    _Float16* myS = &lS[wv][0];

    for (int rb = 0; rb < 4; ++rb) {
        const int r0 = wv * 64 + rb * 16;

        // Q fragment from global (read exactly once, before this row-block's
        // in-place output store below)
        f16x8 aq = *(const f16x8*)(qkv_b0 + (size_t)(r0 + fr) * 1536 + h * 32 + fg * 8);

        // ---- pass 1: S = scale*QK^T + bias, track row max ----
        float smax[4] = { -1e30f, -1e30f, -1e30f, -1e30f };
#pragma unroll 4
        for (int jt = 0; jt < 16; ++jt) {
            f16x8 bk = *(const f16x8*)(qkv_b0 + (size_t)(jt * 16 + fr) * 1536 + 512 + h * 32 + fg * 8);
            f32x4 s = { 0.f, 0.f, 0.f, 0.f };
            s = MFMA16(aq, bk, s);
            const int j  = jt * 16 + fr;      // D col = lane&15
            const int jh = j >> 5, jw = j & 31;
#pragma unroll
            for (int r = 0; r < 4; ++r) {
                const int i  = r0 + fg * 4 + r;   // D row = (lane>>4)*4+r
                const int ih = i >> 5, iw = i & 31;
                float sv = s[r] * ATT_SCALE + lbias[(ih - jh + 7) * 63 + (iw - jw + 31)];
                smax[r] = fmaxf(smax[r], sv);
                myS[(fg * 4 + r) * 264 + j] = (_Float16)sv;
            }
        }
        // row max: reduce across the 16 lanes of each group
#pragma unroll
        for (int m = 1; m <= 8; m <<= 1)
#pragma unroll
            for (int r = 0; r < 4; ++r)
                smax[r] = fmaxf(smax[r], __shfl_xor(smax[r], m));
        // redistribute: lane needs max of row fr (rows q*4+r live in group q)
        float rmax;
        {
            float m0 = __shfl(smax[0], (fr >> 2) << 4);
            float m1 = __shfl(smax[1], (fr >> 2) << 4);
            float m2 = __shfl(smax[2], (fr >> 2) << 4);
            float m3 = __shfl(smax[3], (fr >> 2) << 4);
            float ma = (fr & 1) ? m1 : m0;
            float mb = (fr & 1) ? m3 : m2;
            rmax = (fr & 2) ? mb : ma;
        }
        // wave-internal: make sure S writes land before reads
        asm volatile("s_waitcnt lgkmcnt(0)" ::: "memory");

        // ---- pass 2: P = exp(S - max) as A-fragments, row sums ----
        f16x8 pa[8];
        float rsum = 0.f;
#pragma unroll
        for (int kc = 0; kc < 8; ++kc) {
            f16x8 sv = *(const f16x8*)(&myS[fr * 264 + kc * 32 + fg * 8]);
            f16x8 ph;
#pragma unroll
            for (int jj = 0; jj < 8; ++jj) {
                float p = __expf((float)sv[jj] - rmax);
                rsum += p;
                ph[jj] = (_Float16)p;
            }
            pa[kc] = ph;
        }
        rsum += __shfl_xor(rsum, 16);
        rsum += __shfl_xor(rsum, 32);

        // ---- PV ----
        f32x4 o[2] = {};
#pragma unroll
        for (int kc = 0; kc < 8; ++kc) {
            f16x8 bv0 = *(const f16x8*)(&lVt[(fr     ) * 264 + kc * 32 + fg * 8]);
            f16x8 bv1 = *(const f16x8*)(&lVt[(fr + 16) * 264 + kc * 32 + fg * 8]);
            o[0] = MFMA16(pa[kc], bv0, o[0]);
            o[1] = MFMA16(pa[kc], bv1, o[1]);
        }
        // sums for my 4 output rows (fg*4+r) live in lane (fg*4+r) of group 0
        float os[4];
#pragma unroll
        for (int r = 0; r < 4; ++r) os[r] = __shfl(rsum, fg * 4 + r);

        // in-place store over q-slice (rows of this row-block only)
#pragma unroll
        for (int ni = 0; ni < 2; ++ni)
#pragma unroll
            for (int r = 0; r < 4; ++r) {
                const int i = r0 + fg * 4 + r;
                const int d = ni * 16 + fr;
                qkv_b0[(size_t)i * 1536 + h * 32 + d] = (_Float16)(o[ni][r] / os[r]);
            }
    }
}

// ---------------------------------------------------------------------------
extern "C" void kernel_launch(void* const* d_in, const int* in_sizes, int n_in,
                              void* d_out, int out_size, void* d_ws, size_t ws_size,
                              hipStream_t stream)
{
    (void)in_sizes; (void)n_in;
    const float* x      = (const float*)d_in[0];
    // d_in[1] = q_global (unused by reference)
    const float* qkv_w  = (const float*)d_in[2];
    const float* qkv_b  = (const float*)d_in[3];
    const float* proj_w = (const float*)d_in[4];
    const float* proj_b = (const float*)d_in[5];
    const float* rpb    = (const float*)d_in[6];
    // d_in[7]=wh(8), d_in[8]=ww(32): compile-time constants here
    float* out = (float*)d_out;

    const int M  = 128 * 256;  // 32768
    const int Cd = 512, N3 = 1536;

    // workspace: qkv fp16 only (96 MB); attn output overwrites the q-slice.
    const size_t need = (size_t)M * N3 * sizeof(_Float16);
    if (ws_size < need) {
        // ws too small: DO NOT launch (would write OOB and wedge the
        // container). Deterministic wrong-but-safe zeros instead; the finite
        // absmax in the bench report is the diagnostic signal.
        hipMemsetAsync(d_out, 0, (size_t)out_size * sizeof(float), stream);
        return;
    }

    _Float16* qkvh = (_Float16*)d_ws;

    k_qkv_gemm<<<dim3(M / 64, N3 / 64), 256, 0, stream>>>(x, qkv_w, qkv_b, qkvh, M, N3, Cd);
    k_attn<<<dim3(128 * 16), 256, 0, stream>>>(qkvh, rpb);
    k_proj_gemm<<<dim3(M / 64, Cd / 64), 256, 0, stream>>>(qkvh, N3, proj_w, proj_b, out, M, Cd, Cd);
}

// Round 8
// 365.729 us; speedup vs baseline: 1.3957x; 1.3957x over previous
//
#include <hip/hip_runtime.h>
#include <hip/hip_fp16.h>
#include <cstdint>

typedef _Float16 f16x8 __attribute__((ext_vector_type(8)));
typedef _Float16 f16x4 __attribute__((ext_vector_type(4)));
typedef float    f32x4 __attribute__((ext_vector_type(4)));

#define MFMA16(a, b, c) __builtin_amdgcn_mfma_f32_16x16x32_f16((a), (b), (c), 0, 0, 0)

// async global->LDS, 16B per lane; LDS dest = wave-uniform base + lane*16
__device__ __forceinline__ void async16(_Float16* lds, const _Float16* g) {
    __builtin_amdgcn_global_load_lds(
        (const __attribute__((address_space(1))) void*)g,
        (__attribute__((address_space(3))) void*)lds, 16, 0, 0);
}

// ---------------------------------------------------------------------------
// fp32 -> fp16 convert, 8 elems/thread, exact grid (n % 2048 == 0 for all uses)
// ---------------------------------------------------------------------------
__global__ __launch_bounds__(256) void k_cvt(
    const float* __restrict__ src, _Float16* __restrict__ dst)
{
    const int i = blockIdx.x * 256 + threadIdx.x;
    const float4 a = ((const float4*)src)[2 * i];
    const float4 b = ((const float4*)src)[2 * i + 1];
    f16x8 o = { (_Float16)a.x, (_Float16)a.y, (_Float16)a.z, (_Float16)a.w,
                (_Float16)b.x, (_Float16)b.y, (_Float16)b.z, (_Float16)b.w };
    ((f16x8*)dst)[i] = o;
}

// ---------------------------------------------------------------------------
// fp16 GEMM, C[m][n] = sum_k A[m][k]*B[n][k] + bias[n]  (both K-contiguous)
// 128x128 tile, BK=64, 256 thr (4 waves, each 64x64 = 4x4 MFMA frags).
// Staging: global_load_lds width=16, linear LDS dest + inverse-swizzled
// global source (chunk ^= row&7, involution; rule 21) -> swizzled ds_read
// is 2-way-bank free. 1D grid, n-fastest tile order + bijective XCD swizzle
// (T1): the nTilesN tiles sharing one A-slab run on one XCD -> L2 locality.
// ---------------------------------------------------------------------------
__global__ __launch_bounds__(256) void k_gemm_f16(
    const _Float16* __restrict__ A, int lda,
    const _Float16* __restrict__ B, int ldb,
    const float* __restrict__ bias,
    _Float16* __restrict__ C, int ldc,
    int K, int nTilesN, int cpx)
{
    __shared__ _Float16 lA[128 * 64];
    __shared__ _Float16 lB[128 * 64];
    const int t    = threadIdx.x;
    const int lane = t & 63, wv = t >> 6;
    const int fr = lane & 15, fg = lane >> 4;
    const int wrow = (wv >> 1) * 64, wcol = (wv & 1) * 64;

    const int gid  = (blockIdx.x & 7) * cpx + (blockIdx.x >> 3);
    const int row0 = (gid / nTilesN) * 128;
    const int col0 = (gid % nTilesN) * 128;

    const int rowLane = lane >> 3;                    // 0..7 within 8-row strip
    const int colOff  = ((lane & 7) ^ rowLane) * 8;   // pre-swizzled src chunk
    const int wvr = wv * 32;                          // wave's staging rows

    const _Float16* Ag = A + (size_t)(row0 + wvr + rowLane) * lda + colOff;
    const _Float16* Bg = B + (size_t)(col0 + wvr + rowLane) * ldb + colOff;
    _Float16* lAw = &lA[wvr * 64];
    _Float16* lBw = &lB[wvr * 64];

    f32x4 acc[4][4] = {};

    for (int k0 = 0; k0 < K; k0 += 64) {
#pragma unroll
        for (int i = 0; i < 4; ++i) {
            async16(lAw + i * 8 * 64, Ag + k0 + (size_t)i * 8 * lda);
            async16(lBw + i * 8 * 64, Bg + k0 + (size_t)i * 8 * ldb);
        }
        __syncthreads();   // compiler drains vmcnt(0) before s_barrier
#pragma unroll
        for (int kk = 0; kk < 2; ++kk) {
            f16x8 af[4], bf[4];
#pragma unroll
            for (int mi = 0; mi < 4; ++mi) {
                const int ra = wrow + mi * 16 + fr;
                const int rb = wcol + mi * 16 + fr;
                const int ch = ((kk * 4 + fg) ^ (fr & 7)) * 8;
                af[mi] = *(const f16x8*)&lA[ra * 64 + ch];
                bf[mi] = *(const f16x8*)&lB[rb * 64 + ch];
            }
#pragma unroll
            for (int mi = 0; mi < 4; ++mi)
#pragma unroll
                for (int ni = 0; ni < 4; ++ni)
                    acc[mi][ni] = MFMA16(af[mi], bf[ni], acc[mi][ni]);
        }
        __syncthreads();   // LDS consumed; next iter may overwrite
    }

    // D layout: col=lane&15, row=(lane>>4)*4+r  [m89-verified]
#pragma unroll
    for (int ni = 0; ni < 4; ++ni) {
        const int col = col0 + wcol + ni * 16 + fr;
        const float bb = bias[col];
#pragma unroll
        for (int mi = 0; mi < 4; ++mi)
#pragma unroll
            for (int r = 0; r < 4; ++r) {
                const int row = row0 + wrow + mi * 16 + fg * 4 + r;
                C[(size_t)row * ldc + col] = (_Float16)(acc[mi][ni][r] + bb);
            }
    }
}

// ---------------------------------------------------------------------------
// Proj GEMM (unchanged): A fp16 [M][512] row stride lda, B fp32 [N][K],
// C fp32 [M][N] (+bias). 64x64 tile.
// ---------------------------------------------------------------------------
__global__ __launch_bounds__(256) void k_proj_gemm(
    const _Float16* __restrict__ A, int lda, const float* __restrict__ B,
    const float* __restrict__ bias, float* __restrict__ C,
    int M, int N, int K)
{
    __shared__ _Float16 lA[64 * 64];
    __shared__ _Float16 lB[64 * 64];
    const int t    = threadIdx.x;
    const int lane = t & 63, wv = t >> 6;
    const int wr = (wv >> 1) * 32, wc = (wv & 1) * 32;
    const int fr = lane & 15, fg = lane >> 4;
    const int srow = t >> 2;
    const int scol = (t & 3) * 16;

    const _Float16* Ag = A + (size_t)(blockIdx.x * 64 + srow) * lda + scol;
    const float*    Bg = B + (size_t)(blockIdx.y * 64 + srow) * K + scol;

    f32x4 acc[2][2] = {};

    for (int k0 = 0; k0 < K; k0 += 64) {
#pragma unroll
        for (int q = 0; q < 2; ++q) {
            f16x8 av = *(const f16x8*)(Ag + k0 + q * 8);
            int bo = ((scol + q * 8) * 2) ^ ((srow & 7) << 4);
            *(f16x8*)((char*)lA + srow * 128 + bo) = av;
        }
#pragma unroll
        for (int q = 0; q < 4; ++q) {
            float4 bv = *(const float4*)(Bg + k0 + q * 4);
            int bo = ((scol + q * 4) * 2) ^ ((srow & 7) << 4);
            f16x4 bh = { (_Float16)bv.x, (_Float16)bv.y, (_Float16)bv.z, (_Float16)bv.w };
            *(f16x4*)((char*)lB + srow * 128 + bo) = bh;
        }
        __syncthreads();
#pragma unroll
        for (int kc = 0; kc < 2; ++kc) {
            const int kb = kc * 64 + fg * 16;
            f16x8 a0, a1, b0, b1;
            { int r = wr + fr;      a0 = *(const f16x8*)((char*)lA + r * 128 + (kb ^ ((r & 7) << 4))); }
            { int r = wr + 16 + fr; a1 = *(const f16x8*)((char*)lA + r * 128 + (kb ^ ((r & 7) << 4))); }
            { int r = wc + fr;      b0 = *(const f16x8*)((char*)lB + r * 128 + (kb ^ ((r & 7) << 4))); }
            { int r = wc + 16 + fr; b1 = *(const f16x8*)((char*)lB + r * 128 + (kb ^ ((r & 7) << 4))); }
            acc[0][0] = MFMA16(a0, b0, acc[0][0]);
            acc[0][1] = MFMA16(a0, b1, acc[0][1]);
            acc[1][0] = MFMA16(a1, b0, acc[1][0]);
            acc[1][1] = MFMA16(a1, b1, acc[1][1]);
        }
        __syncthreads();
    }
#pragma unroll
    for (int mi = 0; mi < 2; ++mi)
#pragma unroll
        for (int ni = 0; ni < 2; ++ni) {
            const int col = blockIdx.y * 64 + wc + ni * 16 + fr;
            const float bb = bias[col];
#pragma unroll
            for (int r = 0; r < 4; ++r) {
                const int row = blockIdx.x * 64 + wr + mi * 16 + fg * 4 + r;
                C[(size_t)row * N + col] = acc[mi][ni][r] + bb;
            }
        }
}

// ---------------------------------------------------------------------------
// Attention (unchanged): one block (4 waves) per (b,h); in-place q-slice out.
// ---------------------------------------------------------------------------
#define ATT_SCALE 0.17677669529663687f  // 1/sqrt(32)

__global__ __launch_bounds__(256) void k_attn(
    _Float16* __restrict__ qkv, const float* __restrict__ rpb)
{
    __shared__ _Float16 lS[4][16 * 264];
    __shared__ _Float16 lVt[32 * 264];
    __shared__ float    lbias[945];

    const int bh = blockIdx.x;
    const int b = bh >> 4, h = bh & 15;
    const int t = threadIdx.x, wv = t >> 6, lane = t & 63;
    const int fr = lane & 15, fg = lane >> 4;

    _Float16* qkv_b0 = qkv + (size_t)b * 256 * 1536;

    for (int p = t; p < 945; p += 256) lbias[p] = rpb[p * 16 + h];

    {
        const _Float16* vrow = qkv_b0 + (size_t)t * 1536 + 1024 + h * 32;
        f16x8 v0 = *(const f16x8*)(vrow);
        f16x8 v1 = *(const f16x8*)(vrow + 8);
        f16x8 v2 = *(const f16x8*)(vrow + 16);
        f16x8 v3 = *(const f16x8*)(vrow + 24);
#pragma unroll
        for (int d = 0; d < 8; ++d) {
            lVt[(d     ) * 264 + t] = v0[d];
            lVt[(d +  8) * 264 + t] = v1[d];
            lVt[(d + 16) * 264 + t] = v2[d];
            lVt[(d + 24) * 264 + t] = v3[d];
        }
    }
    __syncthreads();

    _Float16* myS = &lS[wv][0];

    for (int rb = 0; rb < 4; ++rb) {
        const int r0 = wv * 64 + rb * 16;

        f16x8 aq = *(const f16x8*)(qkv_b0 + (size_t)(r0 + fr) * 1536 + h * 32 + fg * 8);

        float smax[4] = { -1e30f, -1e30f, -1e30f, -1e30f };
#pragma unroll 4
        for (int jt = 0; jt < 16; ++jt) {
            f16x8 bk = *(const f16x8*)(qkv_b0 + (size_t)(jt * 16 + fr) * 1536 + 512 + h * 32 + fg * 8);
            f32x4 s = { 0.f, 0.f, 0.f, 0.f };
            s = MFMA16(aq, bk, s);
            const int j  = jt * 16 + fr;
            const int jh = j >> 5, jw = j & 31;
#pragma unroll
            for (int r = 0; r < 4; ++r) {
                const int i  = r0 + fg * 4 + r;
                const int ih = i >> 5, iw = i & 31;
                float sv = s[r] * ATT_SCALE + lbias[(ih - jh + 7) * 63 + (iw - jw + 31)];
                smax[r] = fmaxf(smax[r], sv);
                myS[(fg * 4 + r) * 264 + j] = (_Float16)sv;
            }
        }
#pragma unroll
        for (int m = 1; m <= 8; m <<= 1)
#pragma unroll
            for (int r = 0; r < 4; ++r)
                smax[r] = fmaxf(smax[r], __shfl_xor(smax[r], m));
        float rmax;
        {
            float m0 = __shfl(smax[0], (fr >> 2) << 4);
            float m1 = __shfl(smax[1], (fr >> 2) << 4);
            float m2 = __shfl(smax[2], (fr >> 2) << 4);
            float m3 = __shfl(smax[3], (fr >> 2) << 4);
            float ma = (fr & 1) ? m1 : m0;
            float mb = (fr & 1) ? m3 : m2;
            rmax = (fr & 2) ? mb : ma;
        }
        asm volatile("s_waitcnt lgkmcnt(0)" ::: "memory");

        f16x8 pa[8];
        float rsum = 0.f;
#pragma unroll
        for (int kc = 0; kc < 8; ++kc) {
            f16x8 sv = *(const f16x8*)(&myS[fr * 264 + kc * 32 + fg * 8]);
            f16x8 ph;
#pragma unroll
            for (int jj = 0; jj < 8; ++jj) {
                float p = __expf((float)sv[jj] - rmax);
                rsum += p;
                ph[jj] = (_Float16)p;
            }
            pa[kc] = ph;
        }
        rsum += __shfl_xor(rsum, 16);
        rsum += __shfl_xor(rsum, 32);

        f32x4 o[2] = {};
#pragma unroll
        for (int kc = 0; kc < 8; ++kc) {
            f16x8 bv0 = *(const f16x8*)(&lVt[(fr     ) * 264 + kc * 32 + fg * 8]);
            f16x8 bv1 = *(const f16x8*)(&lVt[(fr + 16) * 264 + kc * 32 + fg * 8]);
            o[0] = MFMA16(pa[kc], bv0, o[0]);
            o[1] = MFMA16(pa[kc], bv1, o[1]);
        }
        float os[4];
#pragma unroll
        for (int r = 0; r < 4; ++r) os[r] = __shfl(rsum, fg * 4 + r);

#pragma unroll
        for (int ni = 0; ni < 2; ++ni)
#pragma unroll
            for (int r = 0; r < 4; ++r) {
                const int i = r0 + fg * 4 + r;
                const int d = ni * 16 + fr;
                qkv_b0[(size_t)i * 1536 + h * 32 + d] = (_Float16)(o[ni][r] / os[r]);
            }
    }
}

// ---------------------------------------------------------------------------
extern "C" void kernel_launch(void* const* d_in, const int* in_sizes, int n_in,
                              void* d_out, int out_size, void* d_ws, size_t ws_size,
                              hipStream_t stream)
{
    (void)in_sizes; (void)n_in;
    const float* x      = (const float*)d_in[0];
    const float* qkv_w  = (const float*)d_in[2];
    const float* qkv_b  = (const float*)d_in[3];
    const float* proj_w = (const float*)d_in[4];
    const float* proj_b = (const float*)d_in[5];
    const float* rpb    = (const float*)d_in[6];
    float* out = (float*)d_out;

    const int M  = 128 * 256;  // 32768
    const int Cd = 512, N3 = 1536;

    // ws: qkv fp16 (96 MB). d_out (64 MB, fully rewritten by proj at the end)
    // doubles as scratch for the fp16 copies of x (32 MB) and qkv_w (1.5 MB):
    // cvt writes them, qkv-GEMM reads them, proj overwrites d_out last. No
    // kernel reads d_out after proj starts -> hazard-free.
    const size_t need = (size_t)M * N3 * sizeof(_Float16);
    if (ws_size < need) {
        hipMemsetAsync(d_out, 0, (size_t)out_size * sizeof(float), stream);
        return;
    }

    _Float16* qkvh = (_Float16*)d_ws;
    _Float16* xh   = (_Float16*)d_out;                  // 16.78M halves = 32 MB
    _Float16* qwh  = xh + (size_t)M * Cd;               // 1.5 MB, ends at 33.5 MB

    k_cvt<<<dim3((M * Cd) / 2048), 256, 0, stream>>>(x, xh);
    k_cvt<<<dim3((N3 * Cd) / 2048), 256, 0, stream>>>(qkv_w, qwh);

    // grid = (M/128)*(N3/128) = 256*12 = 3072 tiles; n-fastest; cpx = 3072/8
    k_gemm_f16<<<dim3(3072), 256, 0, stream>>>(xh, Cd, qwh, Cd, qkv_b,
                                               qkvh, N3, Cd, 12, 384);
    k_attn<<<dim3(128 * 16), 256, 0, stream>>>(qkvh, rpb);
    k_proj_gemm<<<dim3(M / 64, Cd / 64), 256, 0, stream>>>(qkvh, N3, proj_w, proj_b, out, M, Cd, Cd);
}